// Round 2
// baseline (393.078 us; speedup 1.0000x reference)
//
#include <hip/hip_runtime.h>
#include <hip/hip_bf16.h>

typedef __attribute__((ext_vector_type(8))) short bf16x8;
typedef __attribute__((ext_vector_type(4))) float f32x4;
typedef unsigned short u16;
typedef unsigned int u32;

// ---------- helpers ----------

__device__ __forceinline__ u16 f2bf(float f) {
  __hip_bfloat16 h = __float2bfloat16(f);
  return *reinterpret_cast<u16*>(&h);
}

__device__ __forceinline__ void async16(const void* g, void* l) {
  __builtin_amdgcn_global_load_lds((const __attribute__((address_space(1))) u32*)g,
                                   (__attribute__((address_space(3))) u32*)l, 16, 0, 0);
}

// ---------- cast f32 -> bf16 (vectorized) ----------

__global__ void cast_bf16(const float4* __restrict__ src, ushort4* __restrict__ dst, int n4) {
  int stride = gridDim.x * blockDim.x;
  for (int i = blockIdx.x * blockDim.x + threadIdx.x; i < n4; i += stride) {
    float4 v = src[i];
    ushort4 o;
    o.x = f2bf(v.x); o.y = f2bf(v.y); o.z = f2bf(v.z); o.w = f2bf(v.w);
    dst[i] = o;
  }
}

// ---------- RoPE cos/sin table: [2048 pos][32 freq] ----------

__global__ void rope_table(float* __restrict__ tcos, float* __restrict__ tsin) {
  int idx = blockIdx.x * blockDim.x + threadIdx.x;
  if (idx >= 2048 * 32) return;
  int c = idx >> 5, j = idx & 31;
  float inv = powf(10000.f, -(float)j * (1.f / 32.f));
  float ang = (float)c * inv;
  tcos[idx] = cosf(ang);
  tsin[idx] = sinf(ang);
}

// ---------- QKV projection GEMM (y = x @ W^T), RoPE fused for Q/K ----------
// x: [4096,1024] bf16 row-major. W: [1024,1024] bf16 row-major (N x K -> B^T input).
// z=0: Q (+rope) -> [B,H,C,D], z=1: K (+rope) -> [B,H,C,D], z=2: V -> [B,H,D,C] (transposed!)

__launch_bounds__(256)
__global__ void qkv_gemm(const u16* __restrict__ xb, const u16* __restrict__ Wqb,
                         const u16* __restrict__ Wkb, const u16* __restrict__ Wvb,
                         const float* __restrict__ tcos, const float* __restrict__ tsin,
                         u16* __restrict__ Qr, u16* __restrict__ Kr, u16* __restrict__ Vt) {
  const int z = blockIdx.z;
  const u16* W = (z == 0) ? Wqb : (z == 1) ? Wkb : Wvb;
  u16* dst = (z == 0) ? Qr : (z == 1) ? Kr : Vt;
  const int m0 = blockIdx.y * 128, n0 = blockIdx.x * 128;
  const int tid = threadIdx.x, w = tid >> 6, lane = tid & 63, g = lane >> 4, cl = lane & 15;
  const int wr = w >> 1, wc = w & 1;
  __shared__ u16 As[128][32], Bs[128][32];
  f32x4 acc[4][4] = {};
  for (int k0 = 0; k0 < 1024; k0 += 32) {
#pragma unroll
    for (int ch = 0; ch < 2; ++ch) {
      int t = tid + ch * 256;
      int row = t >> 2, col = (t & 3) * 8;
      async16(&xb[(size_t)(m0 + row) * 1024 + k0 + col], &As[row][col]);
      async16(&W[(size_t)(n0 + row) * 1024 + k0 + col], &Bs[row][col]);
    }
    __syncthreads();
    bf16x8 af[4], bfr[4];
#pragma unroll
    for (int i = 0; i < 4; ++i) af[i] = *(const bf16x8*)&As[wr * 64 + i * 16 + cl][g * 8];
#pragma unroll
    for (int j = 0; j < 4; ++j) bfr[j] = *(const bf16x8*)&Bs[wc * 64 + j * 16 + cl][g * 8];
#pragma unroll
    for (int i = 0; i < 4; ++i)
#pragma unroll
      for (int j = 0; j < 4; ++j)
        acc[i][j] = __builtin_amdgcn_mfma_f32_16x16x32_bf16(af[i], bfr[j], acc[i][j], 0, 0, 0);
    __syncthreads();
  }
  // epilogue: D-layout col=lane&15, row=(lane>>4)*4+reg
#pragma unroll
  for (int i = 0; i < 4; ++i) {
    int mbase = m0 + wr * 64 + i * 16 + g * 4;
#pragma unroll
    for (int r = 0; r < 4; ++r) {
      int mm = mbase + r;
      int b = mm >> 11, pos = mm & 2047;
      if (z < 2) {
#pragma unroll
        for (int j = 0; j < 2; ++j) {
          int n = n0 + wc * 64 + j * 16 + cl;
          int h = n >> 6, dlo = n & 63;  // dlo in [0,32)
          float a = acc[i][j][r], b2 = acc[i][j + 2][r];
          float cv = tcos[pos * 32 + dlo], sv = tsin[pos * 32 + dlo];
          float o1 = a * cv - b2 * sv;
          float o2 = b2 * cv + a * sv;
          size_t base = ((size_t)(b * 16 + h) * 2048 + pos) * 64;
          dst[base + dlo] = f2bf(o1);
          dst[base + dlo + 32] = f2bf(o2);
        }
      } else {
        // V transposed: Vt[(b*16+h)*64 + d][pos]
#pragma unroll
        for (int j = 0; j < 4; ++j) {
          int n = n0 + wc * 64 + j * 16 + cl;
          int h = n >> 6, d = n & 63;
          dst[((size_t)(b * 16 + h) * 64 + d) * 2048 + pos] = f2bf(acc[i][j][r]);
        }
      }
    }
  }
}

// ---------- flash attention (causal), 4 independent waves per block ----------
// Q/K: [B*H, 2048, 64] bf16.  Vt: [B*H, 64, 2048] bf16.  hid: [B, C, H*D] bf16.

__launch_bounds__(256)
__global__ void attn_kernel(const u16* __restrict__ Qr, const u16* __restrict__ Kr,
                            const u16* __restrict__ Vt, u16* __restrict__ hid) {
  const int qt = gridDim.x - 1 - blockIdx.x;  // heavy tiles first
  const int bh = blockIdx.y;
  const int tid = threadIdx.x, w = tid >> 6, lane = tid & 63, g = lane >> 4, cl = lane & 15;
  const int b = bh >> 4, h = bh & 15;
  const int qbase = qt * 64 + w * 16;
  const u16* Qp = Qr + (size_t)bh * 2048 * 64;
  const u16* Kp = Kr + (size_t)bh * 2048 * 64;
  const u16* Vp = Vt + (size_t)bh * 2048 * 64;
  __shared__ u16 P_lds[4][16][64];

  bf16x8 aq[2];
#pragma unroll
  for (int s = 0; s < 2; ++s)
    aq[s] = *(const bf16x8*)&Qp[(size_t)(qbase + cl) * 64 + s * 32 + g * 8];

  f32x4 o[4] = {};
  float mrow[4], lrow[4];
#pragma unroll
  for (int r = 0; r < 4; ++r) { mrow[r] = -__builtin_inff(); lrow[r] = 0.f; }

  for (int kt = 0; kt <= qt; ++kt) {
    f32x4 s[4] = {};
#pragma unroll
    for (int n = 0; n < 4; ++n)
#pragma unroll
      for (int ks = 0; ks < 2; ++ks) {
        bf16x8 bk = *(const bf16x8*)&Kp[(size_t)(kt * 64 + n * 16 + cl) * 64 + ks * 32 + g * 8];
        s[n] = __builtin_amdgcn_mfma_f32_16x16x32_bf16(aq[ks], bk, s[n], 0, 0, 0);
      }
    // scale + causal mask (mask only on the diagonal tile)
    if (kt == qt) {
#pragma unroll
      for (int n = 0; n < 4; ++n)
#pragma unroll
        for (int r = 0; r < 4; ++r) {
          int q = qbase + g * 4 + r, k = kt * 64 + n * 16 + cl;
          s[n][r] = (k <= q) ? s[n][r] * 0.125f : -__builtin_inff();
        }
    } else {
#pragma unroll
      for (int n = 0; n < 4; ++n)
#pragma unroll
        for (int r = 0; r < 4; ++r) s[n][r] *= 0.125f;
    }
    // row max (16-lane groups hold a row)
    float pmax[4];
#pragma unroll
    for (int r = 0; r < 4; ++r) {
      float v = fmaxf(fmaxf(s[0][r], s[1][r]), fmaxf(s[2][r], s[3][r]));
#pragma unroll
      for (int off = 1; off < 16; off <<= 1) v = fmaxf(v, __shfl_xor(v, off));
      pmax[r] = v;
    }
    float ef[4];
#pragma unroll
    for (int r = 0; r < 4; ++r) {
      float mnew = fmaxf(mrow[r], pmax[r]);
      ef[r] = __expf(mrow[r] - mnew);
      mrow[r] = mnew;
    }
    float rs[4] = {0.f, 0.f, 0.f, 0.f};
#pragma unroll
    for (int n = 0; n < 4; ++n)
#pragma unroll
      for (int r = 0; r < 4; ++r) {
        float p = __expf(s[n][r] - mrow[r]);
        s[n][r] = p;
        rs[r] += p;
      }
#pragma unroll
    for (int r = 0; r < 4; ++r) {
      float v = rs[r];
#pragma unroll
      for (int off = 1; off < 16; off <<= 1) v += __shfl_xor(v, off);
      lrow[r] = lrow[r] * ef[r] + v;
    }
#pragma unroll
    for (int j = 0; j < 4; ++j)
#pragma unroll
      for (int r = 0; r < 4; ++r) o[j][r] *= ef[r];
    // P (D-layout) -> LDS row-major [16 q][64 kv] bf16, per-wave private
#pragma unroll
    for (int n = 0; n < 4; ++n)
#pragma unroll
      for (int r = 0; r < 4; ++r)
        P_lds[w][g * 4 + r][n * 16 + cl] = f2bf(s[n][r]);
    // PV: A = P from LDS, B = V^T contiguous loads (L2-resident)
#pragma unroll
    for (int ks = 0; ks < 2; ++ks) {
      bf16x8 ap = *(const bf16x8*)&P_lds[w][cl][ks * 32 + g * 8];
#pragma unroll
      for (int j = 0; j < 4; ++j) {
        bf16x8 bv = *(const bf16x8*)&Vp[(size_t)(j * 16 + cl) * 2048 + kt * 64 + ks * 32 + g * 8];
        o[j] = __builtin_amdgcn_mfma_f32_16x16x32_bf16(ap, bv, o[j], 0, 0, 0);
      }
    }
  }
  // epilogue: hid[b][q][h*64+d]
#pragma unroll
  for (int j = 0; j < 4; ++j)
#pragma unroll
    for (int r = 0; r < 4; ++r) {
      float val = o[j][r] / lrow[r];
      int q = qbase + g * 4 + r, d = j * 16 + cl;
      hid[((size_t)(b * 2048) + q) * 1024 + h * 64 + d] = f2bf(val);
    }
}

// ---------- output projection: out = hid @ Wo^T (f32 out) ----------

__launch_bounds__(256)
__global__ void out_gemm(const u16* __restrict__ hb, const u16* __restrict__ Wob,
                         float* __restrict__ out) {
  const int m0 = blockIdx.y * 128, n0 = blockIdx.x * 128;
  const int tid = threadIdx.x, w = tid >> 6, lane = tid & 63, g = lane >> 4, cl = lane & 15;
  const int wr = w >> 1, wc = w & 1;
  __shared__ u16 As[128][32], Bs[128][32];
  f32x4 acc[4][4] = {};
  for (int k0 = 0; k0 < 1024; k0 += 32) {
#pragma unroll
    for (int ch = 0; ch < 2; ++ch) {
      int t = tid + ch * 256;
      int row = t >> 2, col = (t & 3) * 8;
      async16(&hb[(size_t)(m0 + row) * 1024 + k0 + col], &As[row][col]);
      async16(&Wob[(size_t)(n0 + row) * 1024 + k0 + col], &Bs[row][col]);
    }
    __syncthreads();
    bf16x8 af[4], bfr[4];
#pragma unroll
    for (int i = 0; i < 4; ++i) af[i] = *(const bf16x8*)&As[wr * 64 + i * 16 + cl][g * 8];
#pragma unroll
    for (int j = 0; j < 4; ++j) bfr[j] = *(const bf16x8*)&Bs[wc * 64 + j * 16 + cl][g * 8];
#pragma unroll
    for (int i = 0; i < 4; ++i)
#pragma unroll
      for (int j = 0; j < 4; ++j)
        acc[i][j] = __builtin_amdgcn_mfma_f32_16x16x32_bf16(af[i], bfr[j], acc[i][j], 0, 0, 0);
    __syncthreads();
  }
#pragma unroll
  for (int i = 0; i < 4; ++i)
#pragma unroll
    for (int r = 0; r < 4; ++r) {
      int m = m0 + wr * 64 + i * 16 + g * 4 + r;
#pragma unroll
      for (int j = 0; j < 4; ++j)
        out[(size_t)m * 1024 + n0 + wc * 64 + j * 16 + cl] = acc[i][j][r];
    }
}

// ---------- launch ----------

extern "C" void kernel_launch(void* const* d_in, const int* in_sizes, int n_in,
                              void* d_out, int out_size, void* d_ws, size_t ws_size,
                              hipStream_t stream) {
  const float* x = (const float*)d_in[0];
  const float* Wq = (const float*)d_in[1];
  const float* Wk = (const float*)d_in[2];
  const float* Wv = (const float*)d_in[3];
  const float* Wo = (const float*)d_in[4];
  float* out = (float*)d_out;

  char* ws = (char*)d_ws;
  size_t off = 0;
  auto alloc = [&](size_t bytes) {
    void* p = ws + off;
    off += (bytes + 255) & ~(size_t)255;
    return p;
  };
  u16* xb = (u16*)alloc(4096ull * 1024 * 2);
  u16* Wqb = (u16*)alloc(1024ull * 1024 * 2);
  u16* Wkb = (u16*)alloc(1024ull * 1024 * 2);
  u16* Wvb = (u16*)alloc(1024ull * 1024 * 2);
  u16* Wob = (u16*)alloc(1024ull * 1024 * 2);
  u16* Qr = (u16*)alloc(4096ull * 1024 * 2);
  u16* Kr = (u16*)alloc(4096ull * 1024 * 2);
  u16* Vt = (u16*)alloc(4096ull * 1024 * 2);
  u16* hid = (u16*)alloc(4096ull * 1024 * 2);
  float* tcos = (float*)alloc(2048ull * 32 * 4);
  float* tsin = (float*)alloc(2048ull * 32 * 4);

  cast_bf16<<<1024, 256, 0, stream>>>((const float4*)x, (ushort4*)xb, 4096 * 1024 / 4);
  cast_bf16<<<512, 256, 0, stream>>>((const float4*)Wq, (ushort4*)Wqb, 1024 * 1024 / 4);
  cast_bf16<<<512, 256, 0, stream>>>((const float4*)Wk, (ushort4*)Wkb, 1024 * 1024 / 4);
  cast_bf16<<<512, 256, 0, stream>>>((const float4*)Wv, (ushort4*)Wvb, 1024 * 1024 / 4);
  cast_bf16<<<512, 256, 0, stream>>>((const float4*)Wo, (ushort4*)Wob, 1024 * 1024 / 4);
  rope_table<<<256, 256, 0, stream>>>(tcos, tsin);

  qkv_gemm<<<dim3(8, 32, 3), 256, 0, stream>>>(xb, Wqb, Wkb, Wvb, tcos, tsin, Qr, Kr, Vt);
  attn_kernel<<<dim3(32, 32), 256, 0, stream>>>(Qr, Kr, Vt, hid);
  out_gemm<<<dim3(8, 32), 256, 0, stream>>>(hid, Wob, out);
}

// Round 3
// 308.591 us; speedup vs baseline: 1.2738x; 1.2738x over previous
//
#include <hip/hip_runtime.h>
#include <hip/hip_bf16.h>

typedef __attribute__((ext_vector_type(8))) short bf16x8;
typedef __attribute__((ext_vector_type(4))) float f32x4;
typedef unsigned short u16;
typedef unsigned int u32;

// ---------- helpers ----------

__device__ __forceinline__ u16 f2bf(float f) {
  __hip_bfloat16 h = __float2bfloat16(f);
  return *reinterpret_cast<u16*>(&h);
}

__device__ __forceinline__ void async16(const void* g, void* l) {
  __builtin_amdgcn_global_load_lds((const __attribute__((address_space(1))) u32*)g,
                                   (__attribute__((address_space(3))) u32*)l, 16, 0, 0);
}

// ---------- cast f32 -> bf16 (vectorized) ----------

__global__ void cast_bf16(const float4* __restrict__ src, ushort4* __restrict__ dst, int n4) {
  int stride = gridDim.x * blockDim.x;
  for (int i = blockIdx.x * blockDim.x + threadIdx.x; i < n4; i += stride) {
    float4 v = src[i];
    ushort4 o;
    o.x = f2bf(v.x); o.y = f2bf(v.y); o.z = f2bf(v.z); o.w = f2bf(v.w);
    dst[i] = o;
  }
}

// four same-size weight casts fused into one launch (blockIdx.y selects array)
__global__ void cast_w4(const float4* __restrict__ w0, const float4* __restrict__ w1,
                        const float4* __restrict__ w2, const float4* __restrict__ w3,
                        ushort4* __restrict__ o0, ushort4* __restrict__ o1,
                        ushort4* __restrict__ o2, ushort4* __restrict__ o3, int n4) {
  const float4* src = (blockIdx.y == 0) ? w0 : (blockIdx.y == 1) ? w1 : (blockIdx.y == 2) ? w2 : w3;
  ushort4* dst = (blockIdx.y == 0) ? o0 : (blockIdx.y == 1) ? o1 : (blockIdx.y == 2) ? o2 : o3;
  int stride = gridDim.x * blockDim.x;
  for (int i = blockIdx.x * blockDim.x + threadIdx.x; i < n4; i += stride) {
    float4 v = src[i];
    ushort4 o;
    o.x = f2bf(v.x); o.y = f2bf(v.y); o.z = f2bf(v.z); o.w = f2bf(v.w);
    dst[i] = o;
  }
}

// ---------- RoPE cos/sin table: [2048 pos][32 freq] ----------

__global__ void rope_table(float* __restrict__ tcos, float* __restrict__ tsin) {
  int idx = blockIdx.x * blockDim.x + threadIdx.x;
  if (idx >= 2048 * 32) return;
  int c = idx >> 5, j = idx & 31;
  float inv = powf(10000.f, -(float)j * (1.f / 32.f));
  float ang = (float)c * inv;
  tcos[idx] = cosf(ang);
  tsin[idx] = sinf(ang);
}

// ---------- QKV projection GEMM (y = x @ W^T), RoPE fused for Q/K ----------
// z=0: Q (+rope) -> [B,H,C,D], z=1: K (+rope) -> [B,H,C,D], z=2: V -> [B,H,D,C] (transposed)

__launch_bounds__(256)
__global__ void qkv_gemm(const u16* __restrict__ xb, const u16* __restrict__ Wqb,
                         const u16* __restrict__ Wkb, const u16* __restrict__ Wvb,
                         const float* __restrict__ tcos, const float* __restrict__ tsin,
                         u16* __restrict__ Qr, u16* __restrict__ Kr, u16* __restrict__ Vt) {
  const int z = blockIdx.z;
  const u16* W = (z == 0) ? Wqb : (z == 1) ? Wkb : Wvb;
  u16* dst = (z == 0) ? Qr : (z == 1) ? Kr : Vt;
  const int m0 = blockIdx.y * 128, n0 = blockIdx.x * 128;
  const int tid = threadIdx.x, w = tid >> 6, lane = tid & 63, g = lane >> 4, cl = lane & 15;
  const int wr = w >> 1, wc = w & 1;
  __shared__ u16 As[128][32], Bs[128][32];
  f32x4 acc[4][4] = {};
  for (int k0 = 0; k0 < 1024; k0 += 32) {
#pragma unroll
    for (int ch = 0; ch < 2; ++ch) {
      int t = tid + ch * 256;
      int row = t >> 2, col = (t & 3) * 8;
      async16(&xb[(size_t)(m0 + row) * 1024 + k0 + col], &As[row][col]);
      async16(&W[(size_t)(n0 + row) * 1024 + k0 + col], &Bs[row][col]);
    }
    __syncthreads();
    bf16x8 af[4], bfr[4];
#pragma unroll
    for (int i = 0; i < 4; ++i) af[i] = *(const bf16x8*)&As[wr * 64 + i * 16 + cl][g * 8];
#pragma unroll
    for (int j = 0; j < 4; ++j) bfr[j] = *(const bf16x8*)&Bs[wc * 64 + j * 16 + cl][g * 8];
#pragma unroll
    for (int i = 0; i < 4; ++i)
#pragma unroll
      for (int j = 0; j < 4; ++j)
        acc[i][j] = __builtin_amdgcn_mfma_f32_16x16x32_bf16(af[i], bfr[j], acc[i][j], 0, 0, 0);
    __syncthreads();
  }
  // epilogue: D-layout col=lane&15, row=(lane>>4)*4+reg
  if (z < 2) {
#pragma unroll
    for (int i = 0; i < 4; ++i) {
      int mbase = m0 + wr * 64 + i * 16 + g * 4;
#pragma unroll
      for (int r = 0; r < 4; ++r) {
        int mm = mbase + r;
        int b = mm >> 11, pos = mm & 2047;
#pragma unroll
        for (int j = 0; j < 2; ++j) {
          int n = n0 + wc * 64 + j * 16 + cl;
          int h = n >> 6, dlo = n & 63;  // dlo in [0,32)
          float a = acc[i][j][r], b2 = acc[i][j + 2][r];
          float cv = tcos[pos * 32 + dlo], sv = tsin[pos * 32 + dlo];
          float o1 = a * cv - b2 * sv;
          float o2 = b2 * cv + a * sv;
          size_t base = ((size_t)(b * 16 + h) * 2048 + pos) * 64;
          dst[base + dlo] = f2bf(o1);
          dst[base + dlo + 32] = f2bf(o2);
        }
      }
    }
  } else {
    // V transposed: Vt[(b*16+h)*64 + d][pos], pos contiguous -> ushort4 stores
#pragma unroll
    for (int i = 0; i < 4; ++i) {
      int mbase = m0 + wr * 64 + i * 16 + g * 4;  // multiple of 4
      int b = mbase >> 11, pos = mbase & 2047;
#pragma unroll
      for (int j = 0; j < 4; ++j) {
        int n = n0 + wc * 64 + j * 16 + cl;
        int h = n >> 6, d = n & 63;
        ushort4 v4;
        v4.x = f2bf(acc[i][j][0]);
        v4.y = f2bf(acc[i][j][1]);
        v4.z = f2bf(acc[i][j][2]);
        v4.w = f2bf(acc[i][j][3]);
        *(ushort4*)&dst[((size_t)(b * 16 + h) * 64 + d) * 2048 + pos] = v4;
      }
    }
  }
}

// ---------- flash attention (causal), ONE wave per block, QBLK=16 ----------
// Q/K: [B*H, 2048, 64] bf16.  Vt: [B*H, 64, 2048] bf16.  hid: [B, C, H*D] bf16.
// Grid: 4096 1-wave blocks. XCD-swizzle: 4 bh per XCD (K/V 2MB < 4MB L2); heavy qt first.

__launch_bounds__(64)
__global__ void attn_kernel(const u16* __restrict__ Qr, const u16* __restrict__ Kr,
                            const u16* __restrict__ Vt, u16* __restrict__ hid) {
  const int bid = blockIdx.x;
  const int xcd = bid & 7, jj = bid >> 3;
  const int bh = xcd * 4 + (jj >> 7);
  const int qt = 127 - (jj & 127);  // heavy tiles first
  const int lane = threadIdx.x, g = lane >> 4, cl = lane & 15;
  const int b = bh >> 4, h = bh & 15;
  const int qbase = qt * 16;
  const u16* Qp = Qr + (size_t)bh * 2048 * 64;
  const u16* Kp = Kr + (size_t)bh * 2048 * 64;
  const u16* Vp = Vt + (size_t)bh * 2048 * 64;
  __shared__ u16 P_lds[16][64];

  bf16x8 aq[2];
#pragma unroll
  for (int s = 0; s < 2; ++s)
    aq[s] = *(const bf16x8*)&Qp[(size_t)(qbase + cl) * 64 + s * 32 + g * 8];

  f32x4 o[4] = {};
  float mrow[4], lrow[4];
#pragma unroll
  for (int r = 0; r < 4; ++r) { mrow[r] = -__builtin_inff(); lrow[r] = 0.f; }

  const int ktmax = qbase >> 6;
  for (int kt = 0; kt <= ktmax; ++kt) {
    f32x4 s[4] = {};
#pragma unroll
    for (int n = 0; n < 4; ++n)
#pragma unroll
      for (int ks = 0; ks < 2; ++ks) {
        bf16x8 bk = *(const bf16x8*)&Kp[(size_t)(kt * 64 + n * 16 + cl) * 64 + ks * 32 + g * 8];
        s[n] = __builtin_amdgcn_mfma_f32_16x16x32_bf16(aq[ks], bk, s[n], 0, 0, 0);
      }
    // scale + causal mask (mask only on the diagonal tile)
    if (kt == ktmax) {
#pragma unroll
      for (int n = 0; n < 4; ++n)
#pragma unroll
        for (int r = 0; r < 4; ++r) {
          int q = qbase + g * 4 + r, k = kt * 64 + n * 16 + cl;
          s[n][r] = (k <= q) ? s[n][r] * 0.125f : -__builtin_inff();
        }
    } else {
#pragma unroll
      for (int n = 0; n < 4; ++n)
#pragma unroll
        for (int r = 0; r < 4; ++r) s[n][r] *= 0.125f;
    }
    // row max (each q-row lives on 16 lanes)
    float pmax[4];
#pragma unroll
    for (int r = 0; r < 4; ++r) {
      float v = fmaxf(fmaxf(s[0][r], s[1][r]), fmaxf(s[2][r], s[3][r]));
#pragma unroll
      for (int off = 1; off < 16; off <<= 1) v = fmaxf(v, __shfl_xor(v, off));
      pmax[r] = v;
    }
    float ef[4];
#pragma unroll
    for (int r = 0; r < 4; ++r) {
      float mnew = fmaxf(mrow[r], pmax[r]);
      ef[r] = __expf(mrow[r] - mnew);
      mrow[r] = mnew;
    }
    float rs[4] = {0.f, 0.f, 0.f, 0.f};
#pragma unroll
    for (int n = 0; n < 4; ++n)
#pragma unroll
      for (int r = 0; r < 4; ++r) {
        float p = __expf(s[n][r] - mrow[r]);
        s[n][r] = p;
        rs[r] += p;
      }
#pragma unroll
    for (int r = 0; r < 4; ++r) {
      float v = rs[r];
#pragma unroll
      for (int off = 1; off < 16; off <<= 1) v += __shfl_xor(v, off);
      lrow[r] = lrow[r] * ef[r] + v;
    }
#pragma unroll
    for (int j = 0; j < 4; ++j)
#pragma unroll
      for (int r = 0; r < 4; ++r) o[j][r] *= ef[r];
    // P (D-layout) -> LDS row-major [16 q][64 kv]; single wave: no barrier needed
#pragma unroll
    for (int n = 0; n < 4; ++n)
#pragma unroll
      for (int r = 0; r < 4; ++r)
        P_lds[g * 4 + r][n * 16 + cl] = f2bf(s[n][r]);
    // PV: A = P from LDS, B = V^T contiguous vector loads (L2-resident)
#pragma unroll
    for (int ks = 0; ks < 2; ++ks) {
      bf16x8 ap = *(const bf16x8*)&P_lds[cl][ks * 32 + g * 8];
#pragma unroll
      for (int j = 0; j < 4; ++j) {
        bf16x8 bv = *(const bf16x8*)&Vp[(size_t)(j * 16 + cl) * 2048 + kt * 64 + ks * 32 + g * 8];
        o[j] = __builtin_amdgcn_mfma_f32_16x16x32_bf16(ap, bv, o[j], 0, 0, 0);
      }
    }
  }
  // epilogue: hid[b][q][h*64+d]
#pragma unroll
  for (int j = 0; j < 4; ++j)
#pragma unroll
    for (int r = 0; r < 4; ++r) {
      float val = o[j][r] / lrow[r];
      int q = qbase + g * 4 + r, d = j * 16 + cl;
      hid[((size_t)(b * 2048) + q) * 1024 + h * 64 + d] = f2bf(val);
    }
}

// ---------- output projection: out = hid @ Wo^T (f32 out) ----------

__launch_bounds__(256)
__global__ void out_gemm(const u16* __restrict__ hb, const u16* __restrict__ Wob,
                         float* __restrict__ out) {
  const int m0 = blockIdx.y * 128, n0 = blockIdx.x * 128;
  const int tid = threadIdx.x, w = tid >> 6, lane = tid & 63, g = lane >> 4, cl = lane & 15;
  const int wr = w >> 1, wc = w & 1;
  __shared__ u16 As[128][32], Bs[128][32];
  f32x4 acc[4][4] = {};
  for (int k0 = 0; k0 < 1024; k0 += 32) {
#pragma unroll
    for (int ch = 0; ch < 2; ++ch) {
      int t = tid + ch * 256;
      int row = t >> 2, col = (t & 3) * 8;
      async16(&hb[(size_t)(m0 + row) * 1024 + k0 + col], &As[row][col]);
      async16(&Wob[(size_t)(n0 + row) * 1024 + k0 + col], &Bs[row][col]);
    }
    __syncthreads();
    bf16x8 af[4], bfr[4];
#pragma unroll
    for (int i = 0; i < 4; ++i) af[i] = *(const bf16x8*)&As[wr * 64 + i * 16 + cl][g * 8];
#pragma unroll
    for (int j = 0; j < 4; ++j) bfr[j] = *(const bf16x8*)&Bs[wc * 64 + j * 16 + cl][g * 8];
#pragma unroll
    for (int i = 0; i < 4; ++i)
#pragma unroll
      for (int j = 0; j < 4; ++j)
        acc[i][j] = __builtin_amdgcn_mfma_f32_16x16x32_bf16(af[i], bfr[j], acc[i][j], 0, 0, 0);
    __syncthreads();
  }
#pragma unroll
  for (int i = 0; i < 4; ++i)
#pragma unroll
    for (int r = 0; r < 4; ++r) {
      int m = m0 + wr * 64 + i * 16 + g * 4 + r;
#pragma unroll
      for (int j = 0; j < 4; ++j)
        out[(size_t)m * 1024 + n0 + wc * 64 + j * 16 + cl] = acc[i][j][r];
    }
}

// ---------- launch ----------

extern "C" void kernel_launch(void* const* d_in, const int* in_sizes, int n_in,
                              void* d_out, int out_size, void* d_ws, size_t ws_size,
                              hipStream_t stream) {
  const float* x = (const float*)d_in[0];
  const float* Wq = (const float*)d_in[1];
  const float* Wk = (const float*)d_in[2];
  const float* Wv = (const float*)d_in[3];
  const float* Wo = (const float*)d_in[4];
  float* out = (float*)d_out;

  char* ws = (char*)d_ws;
  size_t off = 0;
  auto alloc = [&](size_t bytes) {
    void* p = ws + off;
    off += (bytes + 255) & ~(size_t)255;
    return p;
  };
  u16* xb = (u16*)alloc(4096ull * 1024 * 2);
  u16* Wqb = (u16*)alloc(1024ull * 1024 * 2);
  u16* Wkb = (u16*)alloc(1024ull * 1024 * 2);
  u16* Wvb = (u16*)alloc(1024ull * 1024 * 2);
  u16* Wob = (u16*)alloc(1024ull * 1024 * 2);
  u16* Qr = (u16*)alloc(4096ull * 1024 * 2);
  u16* Kr = (u16*)alloc(4096ull * 1024 * 2);
  u16* Vt = (u16*)alloc(4096ull * 1024 * 2);
  u16* hid = (u16*)alloc(4096ull * 1024 * 2);
  float* tcos = (float*)alloc(2048ull * 32 * 4);
  float* tsin = (float*)alloc(2048ull * 32 * 4);

  cast_bf16<<<1024, 256, 0, stream>>>((const float4*)x, (ushort4*)xb, 4096 * 1024 / 4);
  cast_w4<<<dim3(256, 4), 256, 0, stream>>>((const float4*)Wq, (const float4*)Wk,
                                            (const float4*)Wv, (const float4*)Wo,
                                            (ushort4*)Wqb, (ushort4*)Wkb,
                                            (ushort4*)Wvb, (ushort4*)Wob, 1024 * 1024 / 4);
  rope_table<<<256, 256, 0, stream>>>(tcos, tsin);

  qkv_gemm<<<dim3(8, 32, 3), 256, 0, stream>>>(xb, Wqb, Wkb, Wvb, tcos, tsin, Qr, Kr, Vt);
  attn_kernel<<<4096, 64, 0, stream>>>(Qr, Kr, Vt, hid);
  out_gemm<<<dim3(8, 32), 256, 0, stream>>>(hid, Wob, out);
}

// Round 4
// 275.688 us; speedup vs baseline: 1.4258x; 1.1193x over previous
//
#include <hip/hip_runtime.h>
#include <hip/hip_bf16.h>

typedef __attribute__((ext_vector_type(8))) short bf16x8;
typedef __attribute__((ext_vector_type(4))) float f32x4;
typedef unsigned short u16;
typedef unsigned int u32;

// ---------- helpers ----------

__device__ __forceinline__ u16 f2bf(float f) {
  __hip_bfloat16 h = __float2bfloat16(f);
  return *reinterpret_cast<u16*>(&h);
}

__device__ __forceinline__ void async16(const void* g, void* l) {
  __builtin_amdgcn_global_load_lds((const __attribute__((address_space(1))) u32*)g,
                                   (__attribute__((address_space(3))) u32*)l, 16, 0, 0);
}

// ---------- cast f32 -> bf16 (vectorized) ----------

__global__ void cast_bf16(const float4* __restrict__ src, ushort4* __restrict__ dst, int n4) {
  int stride = gridDim.x * blockDim.x;
  for (int i = blockIdx.x * blockDim.x + threadIdx.x; i < n4; i += stride) {
    float4 v = src[i];
    ushort4 o;
    o.x = f2bf(v.x); o.y = f2bf(v.y); o.z = f2bf(v.z); o.w = f2bf(v.w);
    dst[i] = o;
  }
}

__global__ void cast_w4(const float4* __restrict__ w0, const float4* __restrict__ w1,
                        const float4* __restrict__ w2, const float4* __restrict__ w3,
                        ushort4* __restrict__ o0, ushort4* __restrict__ o1,
                        ushort4* __restrict__ o2, ushort4* __restrict__ o3, int n4) {
  const float4* src = (blockIdx.y == 0) ? w0 : (blockIdx.y == 1) ? w1 : (blockIdx.y == 2) ? w2 : w3;
  ushort4* dst = (blockIdx.y == 0) ? o0 : (blockIdx.y == 1) ? o1 : (blockIdx.y == 2) ? o2 : o3;
  int stride = gridDim.x * blockDim.x;
  for (int i = blockIdx.x * blockDim.x + threadIdx.x; i < n4; i += stride) {
    float4 v = src[i];
    ushort4 o;
    o.x = f2bf(v.x); o.y = f2bf(v.y); o.z = f2bf(v.z); o.w = f2bf(v.w);
    dst[i] = o;
  }
}

// ---------- RoPE cos/sin table: [2048 pos][32 freq] ----------

__global__ void rope_table(float* __restrict__ tcos, float* __restrict__ tsin) {
  int idx = blockIdx.x * blockDim.x + threadIdx.x;
  if (idx >= 2048 * 32) return;
  int c = idx >> 5, j = idx & 31;
  float inv = powf(10000.f, -(float)j * (1.f / 32.f));
  float ang = (float)c * inv;
  tcos[idx] = cosf(ang);
  tsin[idx] = sinf(ang);
}

// ---------- QKV projection GEMM (y = x @ W^T), RoPE fused for Q/K ----------
// z=0: Q (+rope) -> [B,H,C,D], z=1: K (+rope) -> [B,H,C,D], z=2: V -> [B,H,D,C] (transposed)

__launch_bounds__(256)
__global__ void qkv_gemm(const u16* __restrict__ xb, const u16* __restrict__ Wqb,
                         const u16* __restrict__ Wkb, const u16* __restrict__ Wvb,
                         const float* __restrict__ tcos, const float* __restrict__ tsin,
                         u16* __restrict__ Qr, u16* __restrict__ Kr, u16* __restrict__ Vt) {
  const int z = blockIdx.z;
  const u16* W = (z == 0) ? Wqb : (z == 1) ? Wkb : Wvb;
  u16* dst = (z == 0) ? Qr : (z == 1) ? Kr : Vt;
  const int m0 = blockIdx.y * 128, n0 = blockIdx.x * 128;
  const int tid = threadIdx.x, w = tid >> 6, lane = tid & 63, g = lane >> 4, cl = lane & 15;
  const int wr = w >> 1, wc = w & 1;
  __shared__ u16 As[128][32], Bs[128][32];
  f32x4 acc[4][4] = {};
  for (int k0 = 0; k0 < 1024; k0 += 32) {
#pragma unroll
    for (int ch = 0; ch < 2; ++ch) {
      int t = tid + ch * 256;
      int row = t >> 2, col = (t & 3) * 8;
      async16(&xb[(size_t)(m0 + row) * 1024 + k0 + col], &As[row][col]);
      async16(&W[(size_t)(n0 + row) * 1024 + k0 + col], &Bs[row][col]);
    }
    __syncthreads();
    bf16x8 af[4], bfr[4];
#pragma unroll
    for (int i = 0; i < 4; ++i) af[i] = *(const bf16x8*)&As[wr * 64 + i * 16 + cl][g * 8];
#pragma unroll
    for (int j = 0; j < 4; ++j) bfr[j] = *(const bf16x8*)&Bs[wc * 64 + j * 16 + cl][g * 8];
#pragma unroll
    for (int i = 0; i < 4; ++i)
#pragma unroll
      for (int j = 0; j < 4; ++j)
        acc[i][j] = __builtin_amdgcn_mfma_f32_16x16x32_bf16(af[i], bfr[j], acc[i][j], 0, 0, 0);
    __syncthreads();
  }
  if (z < 2) {
#pragma unroll
    for (int i = 0; i < 4; ++i) {
      int mbase = m0 + wr * 64 + i * 16 + g * 4;
#pragma unroll
      for (int r = 0; r < 4; ++r) {
        int mm = mbase + r;
        int b = mm >> 11, pos = mm & 2047;
#pragma unroll
        for (int j = 0; j < 2; ++j) {
          int n = n0 + wc * 64 + j * 16 + cl;
          int h = n >> 6, dlo = n & 63;
          float a = acc[i][j][r], b2 = acc[i][j + 2][r];
          float cv = tcos[pos * 32 + dlo], sv = tsin[pos * 32 + dlo];
          float o1 = a * cv - b2 * sv;
          float o2 = b2 * cv + a * sv;
          size_t base = ((size_t)(b * 16 + h) * 2048 + pos) * 64;
          dst[base + dlo] = f2bf(o1);
          dst[base + dlo + 32] = f2bf(o2);
        }
      }
    }
  } else {
#pragma unroll
    for (int i = 0; i < 4; ++i) {
      int mbase = m0 + wr * 64 + i * 16 + g * 4;
      int b = mbase >> 11, pos = mbase & 2047;
#pragma unroll
      for (int j = 0; j < 4; ++j) {
        int n = n0 + wc * 64 + j * 16 + cl;
        int h = n >> 6, d = n & 63;
        ushort4 v4;
        v4.x = f2bf(acc[i][j][0]);
        v4.y = f2bf(acc[i][j][1]);
        v4.z = f2bf(acc[i][j][2]);
        v4.w = f2bf(acc[i][j][3]);
        *(ushort4*)&dst[((size_t)(b * 16 + h) * 64 + d) * 2048 + pos] = v4;
      }
    }
  }
}

// ---------- flash attention (causal), 1 wave/block, QBLK=32, K 2-deep prefetch ----------
// Q/K: [B*H, 2048, 64] bf16.  Vt: [B*H, 64, 2048] bf16.  hid: [B, C, H*D] bf16.

__launch_bounds__(64)
__global__ void attn_kernel(const u16* __restrict__ Qr, const u16* __restrict__ Kr,
                            const u16* __restrict__ Vt, u16* __restrict__ hid) {
  const int bid = blockIdx.x;
  const int xcd = bid & 7, jj = bid >> 3;
  const int bh = xcd * 4 + (jj >> 6);
  const int qt = 63 - (jj & 63);  // heavy tiles first
  const int lane = threadIdx.x, g = lane >> 4, cl = lane & 15;
  const int b = bh >> 4, h = bh & 15;
  const int qbase = qt * 32;
  const u16* Qp = Qr + (size_t)bh * 2048 * 64;
  const u16* Kp = Kr + (size_t)bh * 2048 * 64;
  const u16* Vp = Vt + (size_t)bh * 2048 * 64;
  __shared__ u16 P_lds[32 * 64];  // XOR-swizzled, per-wave private

  // Q fragments: aq[qg*2+ks]
  bf16x8 aq[4];
#pragma unroll
  for (int qg = 0; qg < 2; ++qg)
#pragma unroll
    for (int ks = 0; ks < 2; ++ks)
      aq[qg * 2 + ks] = *(const bf16x8*)&Qp[(size_t)(qbase + qg * 16 + cl) * 64 + ks * 32 + g * 8];

  f32x4 ot[8] = {};             // O^T frags: ot[qg*4+j], rows=d (g*4+r), col=q(cl)
  float mrow[8], lrow[8];       // [qg*4+r]
#pragma unroll
  for (int r = 0; r < 8; ++r) { mrow[r] = -__builtin_inff(); lrow[r] = 0.f; }

  const int ktmax = qt >> 1;

  auto loadK = [&](bf16x8* dst, int kt_) {
#pragma unroll
    for (int n = 0; n < 4; ++n)
#pragma unroll
      for (int ks = 0; ks < 2; ++ks)
        dst[n * 2 + ks] = *(const bf16x8*)&Kp[(size_t)(kt_ * 64 + n * 16 + cl) * 64 + ks * 32 + g * 8];
  };
  auto loadV = [&](bf16x8* dst, int kt_) {
#pragma unroll
    for (int ks = 0; ks < 2; ++ks)
#pragma unroll
      for (int j = 0; j < 4; ++j)
        dst[ks * 4 + j] = *(const bf16x8*)&Vp[(size_t)(j * 16 + cl) * 2048 + kt_ * 64 + ks * 32 + g * 8];
  };

  auto tile = [&](const bf16x8* kf, const bf16x8* bv, int kt_, bool diag) {
    f32x4 s[8] = {};  // s[qg*4+n]: rows=q(g*4+r), col=k(n*16+cl)
#pragma unroll
    for (int qg = 0; qg < 2; ++qg)
#pragma unroll
      for (int n = 0; n < 4; ++n)
#pragma unroll
        for (int ks = 0; ks < 2; ++ks)
          s[qg * 4 + n] = __builtin_amdgcn_mfma_f32_16x16x32_bf16(aq[qg * 2 + ks], kf[n * 2 + ks],
                                                                  s[qg * 4 + n], 0, 0, 0);
    // scale + mask
    if (diag) {
#pragma unroll
      for (int qg = 0; qg < 2; ++qg)
#pragma unroll
        for (int n = 0; n < 4; ++n)
#pragma unroll
          for (int r = 0; r < 4; ++r) {
            int q = qbase + qg * 16 + g * 4 + r, k = kt_ * 64 + n * 16 + cl;
            s[qg * 4 + n][r] = (k <= q) ? s[qg * 4 + n][r] * 0.125f : -__builtin_inff();
          }
    } else {
#pragma unroll
      for (int i = 0; i < 8; ++i)
#pragma unroll
        for (int r = 0; r < 4; ++r) s[i][r] *= 0.125f;
    }
    bf16x8 ap[4];
#pragma unroll
    for (int qg = 0; qg < 2; ++qg) {
      float pmax[4], ef[4];
#pragma unroll
      for (int r = 0; r < 4; ++r) {
        float v = fmaxf(fmaxf(s[qg * 4 + 0][r], s[qg * 4 + 1][r]),
                        fmaxf(s[qg * 4 + 2][r], s[qg * 4 + 3][r]));
#pragma unroll
        for (int off = 1; off < 16; off <<= 1) v = fmaxf(v, __shfl_xor(v, off));
        pmax[r] = v;
      }
#pragma unroll
      for (int r = 0; r < 4; ++r) {
        float mnew = fmaxf(mrow[qg * 4 + r], pmax[r]);
        ef[r] = __expf(mrow[qg * 4 + r] - mnew);
        mrow[qg * 4 + r] = mnew;
      }
      float rs[4] = {0.f, 0.f, 0.f, 0.f};
#pragma unroll
      for (int n = 0; n < 4; ++n)
#pragma unroll
        for (int r = 0; r < 4; ++r) {
          float p = __expf(s[qg * 4 + n][r] - mrow[qg * 4 + r]);
          s[qg * 4 + n][r] = p;
          rs[r] += p;
          int row = qg * 16 + g * 4 + r;
          P_lds[(row * 64 + n * 16 + cl) ^ ((row & 7) << 3)] = f2bf(p);
        }
#pragma unroll
      for (int r = 0; r < 4; ++r) {
        float v = rs[r];
#pragma unroll
        for (int off = 1; off < 16; off <<= 1) v += __shfl_xor(v, off);
        lrow[qg * 4 + r] = lrow[qg * 4 + r] * ef[r] + v;
      }
      // transpose ef to per-lane (for O^T col q=cl)
      int src = ((cl >> 2) << 4) | cl;
      float t0 = __shfl(ef[0], src), t1 = __shfl(ef[1], src);
      float t2 = __shfl(ef[2], src), t3 = __shfl(ef[3], src);
      float eft = (cl & 2) ? ((cl & 1) ? t3 : t2) : ((cl & 1) ? t1 : t0);
#pragma unroll
      for (int j = 0; j < 4; ++j)
#pragma unroll
        for (int r = 0; r < 4; ++r) ot[qg * 4 + j][r] *= eft;
      // read P fragments (B-role for swapped PV)
#pragma unroll
      for (int ks = 0; ks < 2; ++ks) {
        int rowr = qg * 16 + cl;
        ap[qg * 2 + ks] = *(const bf16x8*)&P_lds[(rowr * 64 + ks * 32 + g * 8) ^ ((rowr & 7) << 3)];
      }
    }
    // PV swapped: O^T = V^T * P^T
#pragma unroll
    for (int qg = 0; qg < 2; ++qg)
#pragma unroll
      for (int ks = 0; ks < 2; ++ks)
#pragma unroll
        for (int j = 0; j < 4; ++j)
          ot[qg * 4 + j] = __builtin_amdgcn_mfma_f32_16x16x32_bf16(bv[ks * 4 + j], ap[qg * 2 + ks],
                                                                   ot[qg * 4 + j], 0, 0, 0);
  };

  bf16x8 kA[8], kB[8], bv[8];
  loadK(kA, 0);
  for (int kt = 0; kt <= ktmax; kt += 2) {
    loadV(bv, kt);
    if (kt + 1 <= ktmax) loadK(kB, kt + 1);
    tile(kA, bv, kt, kt == ktmax);
    if (kt + 1 <= ktmax) {
      loadV(bv, kt + 1);
      if (kt + 2 <= ktmax) loadK(kA, kt + 2);
      tile(kB, bv, kt + 1, kt + 1 == ktmax);
    }
  }

  // epilogue: O^T rows d = j*16+g*4+r, col q = qbase+qg*16+cl; transpose l to per-lane
#pragma unroll
  for (int qg = 0; qg < 2; ++qg) {
    int src = ((cl >> 2) << 4) | cl;
    float t0 = __shfl(lrow[qg * 4 + 0], src), t1 = __shfl(lrow[qg * 4 + 1], src);
    float t2 = __shfl(lrow[qg * 4 + 2], src), t3 = __shfl(lrow[qg * 4 + 3], src);
    float lt = (cl & 2) ? ((cl & 1) ? t3 : t2) : ((cl & 1) ? t1 : t0);
    float inv = 1.f / lt;
    int q = qbase + qg * 16 + cl;
#pragma unroll
    for (int j = 0; j < 4; ++j) {
      ushort4 v4;
      v4.x = f2bf(ot[qg * 4 + j][0] * inv);
      v4.y = f2bf(ot[qg * 4 + j][1] * inv);
      v4.z = f2bf(ot[qg * 4 + j][2] * inv);
      v4.w = f2bf(ot[qg * 4 + j][3] * inv);
      *(ushort4*)&hid[((size_t)(b * 2048) + q) * 1024 + h * 64 + j * 16 + g * 4] = v4;
    }
  }
}

// ---------- output projection: out = hid @ Wo^T (f32 out) ----------

__launch_bounds__(256)
__global__ void out_gemm(const u16* __restrict__ hb, const u16* __restrict__ Wob,
                         float* __restrict__ out) {
  const int m0 = blockIdx.y * 128, n0 = blockIdx.x * 128;
  const int tid = threadIdx.x, w = tid >> 6, lane = tid & 63, g = lane >> 4, cl = lane & 15;
  const int wr = w >> 1, wc = w & 1;
  __shared__ u16 As[128][32], Bs[128][32];
  f32x4 acc[4][4] = {};
  for (int k0 = 0; k0 < 1024; k0 += 32) {
#pragma unroll
    for (int ch = 0; ch < 2; ++ch) {
      int t = tid + ch * 256;
      int row = t >> 2, col = (t & 3) * 8;
      async16(&hb[(size_t)(m0 + row) * 1024 + k0 + col], &As[row][col]);
      async16(&Wob[(size_t)(n0 + row) * 1024 + k0 + col], &Bs[row][col]);
    }
    __syncthreads();
    bf16x8 af[4], bfr[4];
#pragma unroll
    for (int i = 0; i < 4; ++i) af[i] = *(const bf16x8*)&As[wr * 64 + i * 16 + cl][g * 8];
#pragma unroll
    for (int j = 0; j < 4; ++j) bfr[j] = *(const bf16x8*)&Bs[wc * 64 + j * 16 + cl][g * 8];
#pragma unroll
    for (int i = 0; i < 4; ++i)
#pragma unroll
      for (int j = 0; j < 4; ++j)
        acc[i][j] = __builtin_amdgcn_mfma_f32_16x16x32_bf16(af[i], bfr[j], acc[i][j], 0, 0, 0);
    __syncthreads();
  }
#pragma unroll
  for (int i = 0; i < 4; ++i)
#pragma unroll
    for (int r = 0; r < 4; ++r) {
      int m = m0 + wr * 64 + i * 16 + g * 4 + r;
#pragma unroll
      for (int j = 0; j < 4; ++j)
        out[(size_t)m * 1024 + n0 + wc * 64 + j * 16 + cl] = acc[i][j][r];
    }
}

// ---------- launch ----------

extern "C" void kernel_launch(void* const* d_in, const int* in_sizes, int n_in,
                              void* d_out, int out_size, void* d_ws, size_t ws_size,
                              hipStream_t stream) {
  const float* x = (const float*)d_in[0];
  const float* Wq = (const float*)d_in[1];
  const float* Wk = (const float*)d_in[2];
  const float* Wv = (const float*)d_in[3];
  const float* Wo = (const float*)d_in[4];
  float* out = (float*)d_out;

  char* ws = (char*)d_ws;
  size_t off = 0;
  auto alloc = [&](size_t bytes) {
    void* p = ws + off;
    off += (bytes + 255) & ~(size_t)255;
    return p;
  };
  u16* xb = (u16*)alloc(4096ull * 1024 * 2);
  u16* Wqb = (u16*)alloc(1024ull * 1024 * 2);
  u16* Wkb = (u16*)alloc(1024ull * 1024 * 2);
  u16* Wvb = (u16*)alloc(1024ull * 1024 * 2);
  u16* Wob = (u16*)alloc(1024ull * 1024 * 2);
  u16* Qr = (u16*)alloc(4096ull * 1024 * 2);
  u16* Kr = (u16*)alloc(4096ull * 1024 * 2);
  u16* Vt = (u16*)alloc(4096ull * 1024 * 2);
  u16* hid = (u16*)alloc(4096ull * 1024 * 2);
  float* tcos = (float*)alloc(2048ull * 32 * 4);
  float* tsin = (float*)alloc(2048ull * 32 * 4);

  cast_bf16<<<1024, 256, 0, stream>>>((const float4*)x, (ushort4*)xb, 4096 * 1024 / 4);
  cast_w4<<<dim3(256, 4), 256, 0, stream>>>((const float4*)Wq, (const float4*)Wk,
                                            (const float4*)Wv, (const float4*)Wo,
                                            (ushort4*)Wqb, (ushort4*)Wkb,
                                            (ushort4*)Wvb, (ushort4*)Wob, 1024 * 1024 / 4);
  rope_table<<<256, 256, 0, stream>>>(tcos, tsin);

  qkv_gemm<<<dim3(8, 32, 3), 256, 0, stream>>>(xb, Wqb, Wkb, Wvb, tcos, tsin, Qr, Kr, Vt);
  attn_kernel<<<2048, 64, 0, stream>>>(Qr, Kr, Vt, hid);
  out_gemm<<<dim3(8, 32), 256, 0, stream>>>(hid, Wob, out);
}